// Round 1
// baseline (311.354 us; speedup 1.0000x reference)
//
#include <hip/hip_runtime.h>
#include <stdint.h>

#define N_SPK 512
#define N_UTT 64
#define DIM   1024
#define NROWS (N_SPK * N_UTT)   // 32768
#define EPS   1e-6f

#define BM 128
#define BN 128
#define BK 32
#define KTILES (DIM / BK)       // 32

typedef __attribute__((ext_vector_type(8))) short short8;
typedef __attribute__((ext_vector_type(4))) float f32x4;

__device__ __forceinline__ float bf2f(short u) {
    union { float f; uint32_t i; } un;
    un.i = ((uint32_t)(uint16_t)u) << 16;
    return un.f;
}
__device__ __forceinline__ uint16_t f2bf(float f) {
    union { float f; uint32_t i; } un; un.f = f;
    uint32_t x = un.i;
    return (uint16_t)((x + 0x7fffu + ((x >> 16) & 1u)) >> 16);
}

// K1: one block per speaker n.
// Pass 1: stream x[n] (256 KB fp32), accumulate S in regs, write bf16(x).
// Then: ssq = ||S||^2 via block reduce; write normalized centroid (bf16).
// Pass 2: re-read bf16(x) (same block wrote it; __syncthreads drains vmcnt),
// per-row xx = x.x, xs = x.S via wave reduce -> pos[row], rnx[row].
__global__ __launch_bounds__(256) void prep_kernel(
    const float* __restrict__ x, const float* __restrict__ wp, const float* __restrict__ bp,
    uint16_t* __restrict__ xb, uint16_t* __restrict__ cmat,
    float* __restrict__ pos, float* __restrict__ rnx)
{
    const int n    = blockIdx.x;
    const int tid  = threadIdx.x;
    const int lane = tid & 63;
    const int wid  = tid >> 6;

    __shared__ float Sh[DIM];
    __shared__ float red[4];

    const float* xn  = x  + (size_t)n * N_UTT * DIM;
    uint16_t*    xbn = xb + (size_t)n * N_UTT * DIM;

    const int d0 = tid * 4;
    float4 S = make_float4(0.f, 0.f, 0.f, 0.f);
    for (int m = 0; m < N_UTT; ++m) {
        const float4 v = *(const float4*)(xn + m * DIM + d0);
        S.x += v.x; S.y += v.y; S.z += v.z; S.w += v.w;
        ushort4 o;
        o.x = f2bf(v.x); o.y = f2bf(v.y); o.z = f2bf(v.z); o.w = f2bf(v.w);
        *(ushort4*)(xbn + m * DIM + d0) = o;
    }
    Sh[d0 + 0] = S.x; Sh[d0 + 1] = S.y; Sh[d0 + 2] = S.z; Sh[d0 + 3] = S.w;

    float css = S.x * S.x + S.y * S.y + S.z * S.z + S.w * S.w;
    #pragma unroll
    for (int off = 1; off < 64; off <<= 1) css += __shfl_xor(css, off);
    if (lane == 0) red[wid] = css;
    __syncthreads();
    const float ssq = red[0] + red[1] + red[2] + red[3];

    // c = l2norm(S/64): c_d = S_d * scale
    {
        const float scale = rsqrtf(fmaxf(ssq * (1.0f / 4096.f), EPS)) * (1.0f / 64.f);
        ushort4 o;
        o.x = f2bf(S.x * scale); o.y = f2bf(S.y * scale);
        o.z = f2bf(S.z * scale); o.w = f2bf(S.w * scale);
        *(ushort4*)(cmat + (size_t)n * DIM + d0) = o;
    }

    // Pass 2: wave wid handles rows m = wid*16 .. wid*16+15
    float Sf[16];
    #pragma unroll
    for (int j = 0; j < 16; ++j) Sf[j] = Sh[lane * 16 + j];

    const float wv = wp[0], bv = bp[0];
    for (int i = 0; i < 16; ++i) {
        const int m = wid * 16 + i;
        const uint16_t* rp = xbn + m * DIM + lane * 16;
        const short8 v0 = *(const short8*)rp;
        const short8 v1 = *(const short8*)(rp + 8);
        float xx = 0.f, xs = 0.f;
        #pragma unroll
        for (int j = 0; j < 8; ++j) { const float f = bf2f(v0[j]); xx += f * f; xs += f * Sf[j]; }
        #pragma unroll
        for (int j = 0; j < 8; ++j) { const float f = bf2f(v1[j]); xx += f * f; xs += f * Sf[8 + j]; }
        #pragma unroll
        for (int off = 1; off < 64; off <<= 1) {
            xx += __shfl_xor(xx, off);
            xs += __shfl_xor(xs, off);
        }
        if (lane == 0) {
            const int row = n * N_UTT + m;
            const float mxx = fmaxf(xx, EPS);
            const float d2  = ssq - 2.f * xs + xx;           // ||S - x||^2
            const float mu  = fmaxf(d2 * (1.0f / 3969.f), EPS); // ||(S-x)/63||^2 guard
            const float cs  = ((xs - xx) * (1.0f / 63.f)) * rsqrtf(mxx) * rsqrtf(mu);
            pos[row] = wv * cs + bv;
            rnx[row] = rsqrtf(mxx);
        }
    }
}

// K2: bf16 MFMA GEMM (A = xb [32768 x 1024], B^T = cmat [512 x 1024]) with
// fused exp/row-sum epilogue. 128x128 tile, BK=32, global_load_lds width-16.
__global__ __launch_bounds__(256) void gemm_lse_kernel(
    const uint16_t* __restrict__ xb, const uint16_t* __restrict__ cmat,
    const float* __restrict__ rnx,
    const float* __restrict__ wp, const float* __restrict__ bp,
    float* __restrict__ sumexp)
{
    __shared__ uint16_t Asm[BM * BK];   // 8 KB
    __shared__ uint16_t Bsm[BN * BK];   // 8 KB

    const int tid   = threadIdx.x;
    const int lane  = tid & 63;
    const int wid   = tid >> 6;
    const int waveM = wid >> 1;
    const int waveN = wid & 1;

    // Swizzle: bid = rtLow(3b) | ct(2b)<<3 | rtHigh<<5 so the 4 col-tiles of a
    // row-tile land on the same XCD (bid%8 equal) within a few dispatches ->
    // A-tile L2 reuse.
    const int bid = blockIdx.x;
    const int rt  = (bid & 7) | ((bid >> 5) << 3);
    const int ct  = (bid >> 3) & 3;

    const int rowBase = rt * BM;
    const int colBase = ct * BN;

    // Staging: chunk s (16 B) for instr i is s = i*256 + tid; LDS slot (srow, skc)
    // holds global chunk kc = skc ^ ((srow>>1)&3)  (bank-conflict swizzle).
    const uint16_t* gA[2];
    const uint16_t* gB[2];
    #pragma unroll
    for (int i = 0; i < 2; ++i) {
        const int s    = i * 256 + tid;
        const int srow = s >> 2;
        const int kc   = (s & 3) ^ ((srow >> 1) & 3);
        gA[i] = xb   + (size_t)(rowBase + srow) * DIM + kc * 8;
        gB[i] = cmat + (size_t)(colBase + srow) * DIM + kc * 8;
    }

    f32x4 acc[4][4];
    #pragma unroll
    for (int i = 0; i < 4; ++i)
        #pragma unroll
        for (int j = 0; j < 4; ++j)
            acc[i][j] = (f32x4){0.f, 0.f, 0.f, 0.f};

    const int cL  = lane & 15;
    const int q   = lane >> 4;
    const int key = (cL >> 1) & 3;
    const int kcs = q ^ key;          // swizzled chunk slot for frag reads

    for (int kt = 0; kt < KTILES; ++kt) {
        __syncthreads();              // previous compute done before overwrite
        const int ko = kt * BK;
        #pragma unroll
        for (int i = 0; i < 2; ++i) {
            __builtin_amdgcn_global_load_lds(
                (const __attribute__((address_space(1))) void*)(gA[i] + ko),
                (__attribute__((address_space(3))) void*)(&Asm[(i * 256 + wid * 64) * 8]),
                16, 0, 0);
            __builtin_amdgcn_global_load_lds(
                (const __attribute__((address_space(1))) void*)(gB[i] + ko),
                (__attribute__((address_space(3))) void*)(&Bsm[(i * 256 + wid * 64) * 8]),
                16, 0, 0);
        }
        __syncthreads();              // staging visible (compiler drains vmcnt)

        short8 a[4], b[4];
        #pragma unroll
        for (int bi = 0; bi < 4; ++bi)
            a[bi] = *(const short8*)&Asm[(waveM * 64 + bi * 16 + cL) * BK + kcs * 8];
        #pragma unroll
        for (int bj = 0; bj < 4; ++bj)
            b[bj] = *(const short8*)&Bsm[(waveN * 64 + bj * 16 + cL) * BK + kcs * 8];

        #pragma unroll
        for (int bi = 0; bi < 4; ++bi)
            #pragma unroll
            for (int bj = 0; bj < 4; ++bj)
                acc[bi][bj] = __builtin_amdgcn_mfma_f32_16x16x32_bf16(
                    a[bi], b[bj], acc[bi][bj], 0, 0, 0);
    }

    // Epilogue: sim = w*cos + b; exclude k==n (diag), row-sum exp, atomicAdd.
    const float wv = wp[0], bv = bp[0];
    #pragma unroll
    for (int bi = 0; bi < 4; ++bi) {
        #pragma unroll
        for (int r = 0; r < 4; ++r) {
            const int R = rowBase + waveM * 64 + bi * 16 + q * 4 + r;
            const float rn = rnx[R];
            const int nrow = R >> 6;
            float s = 0.f;
            #pragma unroll
            for (int bj = 0; bj < 4; ++bj) {
                const int col = colBase + waveN * 64 + bj * 16 + cL;
                const float sim = wv * (acc[bi][bj][r] * rn) + bv;
                const float e = __expf(sim);
                s += (col == nrow) ? 0.f : e;
            }
            #pragma unroll
            for (int off = 1; off < 16; off <<= 1) s += __shfl_xor(s, off);
            if (cL == 0) atomicAdd(&sumexp[R], s);
        }
    }
}

// K3: loss = sum_r log(sumexp_others[r] + exp(pos[r])) - pos[r]
__global__ __launch_bounds__(256) void finalize_kernel(
    const float* __restrict__ pos, const float* __restrict__ sumexp,
    float* __restrict__ out)
{
    const int tid = threadIdx.x;
    float acc = 0.f;
    for (int r = tid; r < NROWS; r += 256) {
        const float p = pos[r];
        acc += __logf(sumexp[r] + __expf(p)) - p;
    }
    #pragma unroll
    for (int off = 1; off < 64; off <<= 1) acc += __shfl_xor(acc, off);
    __shared__ float red[4];
    if ((tid & 63) == 0) red[tid >> 6] = acc;
    __syncthreads();
    if (tid == 0) out[0] = red[0] + red[1] + red[2] + red[3];
}

extern "C" void kernel_launch(void* const* d_in, const int* in_sizes, int n_in,
                              void* d_out, int out_size, void* d_ws, size_t ws_size,
                              hipStream_t stream)
{
    const float* x  = (const float*)d_in[0];
    const float* wp = (const float*)d_in[1];
    const float* bp = (const float*)d_in[2];
    float* out = (float*)d_out;

    char* ws = (char*)d_ws;
    uint16_t* xb   = (uint16_t*)ws;                                   // 64 MB
    uint16_t* cmat = (uint16_t*)(ws + (size_t)NROWS * DIM * 2);       // 1 MB
    float*    pos  = (float*)(ws + (size_t)NROWS * DIM * 2 + (size_t)N_SPK * DIM * 2);
    float*    rnx  = pos + NROWS;
    float*    sumexp = rnx + NROWS;

    hipMemsetAsync(sumexp, 0, NROWS * sizeof(float), stream);
    prep_kernel<<<N_SPK, 256, 0, stream>>>(x, wp, bp, xb, cmat, pos, rnx);
    gemm_lse_kernel<<<(NROWS / BM) * (N_SPK / BN), 256, 0, stream>>>(xb, cmat, rnx, wp, bp, sumexp);
    finalize_kernel<<<1, 256, 0, stream>>>(pos, sumexp, out);
}

// Round 2
// 284.320 us; speedup vs baseline: 1.0951x; 1.0951x over previous
//
#include <hip/hip_runtime.h>
#include <stdint.h>

#define N_SPK 512
#define N_UTT 64
#define DIM   1024
#define NROWS (N_SPK * N_UTT)   // 32768
#define EPS   1e-6f

#define BM 128
#define BN 128
#define BK 32
#define KTILES (DIM / BK)       // 32

typedef __attribute__((ext_vector_type(8))) short short8;
typedef __attribute__((ext_vector_type(4))) float f32x4;

__device__ __forceinline__ uint16_t f2bf(float f) {
    union { float f; uint32_t i; } un; un.f = f;
    uint32_t x = un.i;
    return (uint16_t)((x + 0x7fffu + ((x >> 16) & 1u)) >> 16);
}

// K1a: 4 blocks per speaker, 16 rows each; wave w handles rows w*4..w*4+3.
// Streams fp32 -> bf16 (xb), per-row xx (wave reduce), per-block partial S
// -> LDS reduce -> coalesced global atomicAdd into Sg.
__global__ __launch_bounds__(256) void prep_stream(
    const float* __restrict__ x, uint16_t* __restrict__ xb,
    float* __restrict__ Sg, float* __restrict__ xxg)
{
    const int b    = blockIdx.x;
    const int n    = b >> 2;
    const int g    = b & 3;
    const int tid  = threadIdx.x;
    const int lane = tid & 63;
    const int w    = tid >> 6;

    const float* xn  = x  + (size_t)n * N_UTT * DIM;
    uint16_t*    xbn = xb + (size_t)n * N_UTT * DIM;

    float Sp[16];
    #pragma unroll
    for (int j = 0; j < 16; ++j) Sp[j] = 0.f;

    #pragma unroll
    for (int i = 0; i < 4; ++i) {
        const int m = g * 16 + w * 4 + i;
        const float* rp = xn  + (size_t)m * DIM;
        uint16_t*    op = xbn + (size_t)m * DIM;
        float xxp = 0.f;
        #pragma unroll
        for (int j = 0; j < 4; ++j) {
            const float4 v = *(const float4*)(rp + j * 256 + lane * 4);
            xxp += v.x * v.x + v.y * v.y + v.z * v.z + v.w * v.w;
            Sp[j * 4 + 0] += v.x; Sp[j * 4 + 1] += v.y;
            Sp[j * 4 + 2] += v.z; Sp[j * 4 + 3] += v.w;
            ushort4 o;
            o.x = f2bf(v.x); o.y = f2bf(v.y); o.z = f2bf(v.z); o.w = f2bf(v.w);
            *(ushort4*)(op + j * 256 + lane * 4) = o;
        }
        #pragma unroll
        for (int off = 1; off < 64; off <<= 1) xxp += __shfl_xor(xxp, off);
        if (lane == 0) xxg[n * N_UTT + m] = xxp;
    }

    __shared__ float Sh[4][DIM];
    #pragma unroll
    for (int j = 0; j < 4; ++j)
        *(float4*)&Sh[w][j * 256 + lane * 4] =
            make_float4(Sp[j * 4], Sp[j * 4 + 1], Sp[j * 4 + 2], Sp[j * 4 + 3]);
    __syncthreads();

    const int d0 = tid * 4;
    float4 a = *(const float4*)&Sh[0][d0];
    const float4 b1 = *(const float4*)&Sh[1][d0];
    const float4 b2 = *(const float4*)&Sh[2][d0];
    const float4 b3 = *(const float4*)&Sh[3][d0];
    a.x += b1.x + b2.x + b3.x; a.y += b1.y + b2.y + b3.y;
    a.z += b1.z + b2.z + b3.z; a.w += b1.w + b2.w + b3.w;
    float* Sgn = Sg + (size_t)n * DIM + d0;
    atomicAdd(Sgn + 0, a.x); atomicAdd(Sgn + 1, a.y);
    atomicAdd(Sgn + 2, a.z); atomicAdd(Sgn + 3, a.w);
}

// K1b: per-speaker centroid normalize + ssq.
__global__ __launch_bounds__(256) void centroid_kernel(
    const float* __restrict__ Sg, uint16_t* __restrict__ cmat, float* __restrict__ ssqg)
{
    const int n   = blockIdx.x;
    const int tid = threadIdx.x;
    const int d0  = tid * 4;

    const float4 S = *(const float4*)(Sg + (size_t)n * DIM + d0);
    float css = S.x * S.x + S.y * S.y + S.z * S.z + S.w * S.w;
    #pragma unroll
    for (int off = 1; off < 64; off <<= 1) css += __shfl_xor(css, off);
    __shared__ float red[4];
    if ((tid & 63) == 0) red[tid >> 6] = css;
    __syncthreads();
    const float ssq = red[0] + red[1] + red[2] + red[3];

    const float scale = rsqrtf(fmaxf(ssq * (1.0f / 4096.f), EPS)) * (1.0f / 64.f);
    ushort4 o;
    o.x = f2bf(S.x * scale); o.y = f2bf(S.y * scale);
    o.z = f2bf(S.z * scale); o.w = f2bf(S.w * scale);
    *(ushort4*)(cmat + (size_t)n * DIM + d0) = o;
    if (tid == 0) ssqg[n] = ssq;
}

// K2: bf16 MFMA GEMM (A = xb [32768 x 1024], B^T = cmat [512 x 1024]).
// Epilogue: off-diag sim = w*dot*rn + b; diag reconstructs cos_self from
// (dot*|S|, xx, ssq), stores pos[R], includes exp(pos) in the row sum.
__global__ __launch_bounds__(256) void gemm_lse_kernel(
    const uint16_t* __restrict__ xb, const uint16_t* __restrict__ cmat,
    const float* __restrict__ xxg, const float* __restrict__ ssqg,
    const float* __restrict__ wp, const float* __restrict__ bp,
    float* __restrict__ sumexp, float* __restrict__ pos)
{
    __shared__ uint16_t Asm[BM * BK];   // 8 KB
    __shared__ uint16_t Bsm[BN * BK];   // 8 KB

    const int tid   = threadIdx.x;
    const int lane  = tid & 63;
    const int wid   = tid >> 6;
    const int waveM = wid >> 1;
    const int waveN = wid & 1;

    const int bid = blockIdx.x;
    const int rt  = (bid & 7) | ((bid >> 5) << 3);
    const int ct  = (bid >> 3) & 3;

    const int rowBase = rt * BM;
    const int colBase = ct * BN;

    const uint16_t* gA[2];
    const uint16_t* gB[2];
    #pragma unroll
    for (int i = 0; i < 2; ++i) {
        const int s    = i * 256 + tid;
        const int srow = s >> 2;
        const int kc   = (s & 3) ^ ((srow >> 1) & 3);
        gA[i] = xb   + (size_t)(rowBase + srow) * DIM + kc * 8;
        gB[i] = cmat + (size_t)(colBase + srow) * DIM + kc * 8;
    }

    f32x4 acc[4][4];
    #pragma unroll
    for (int i = 0; i < 4; ++i)
        #pragma unroll
        for (int j = 0; j < 4; ++j)
            acc[i][j] = (f32x4){0.f, 0.f, 0.f, 0.f};

    const int cL  = lane & 15;
    const int q   = lane >> 4;
    const int key = (cL >> 1) & 3;
    const int kcs = q ^ key;

    for (int kt = 0; kt < KTILES; ++kt) {
        __syncthreads();
        const int ko = kt * BK;
        #pragma unroll
        for (int i = 0; i < 2; ++i) {
            __builtin_amdgcn_global_load_lds(
                (const __attribute__((address_space(1))) void*)(gA[i] + ko),
                (__attribute__((address_space(3))) void*)(&Asm[(i * 256 + wid * 64) * 8]),
                16, 0, 0);
            __builtin_amdgcn_global_load_lds(
                (const __attribute__((address_space(1))) void*)(gB[i] + ko),
                (__attribute__((address_space(3))) void*)(&Bsm[(i * 256 + wid * 64) * 8]),
                16, 0, 0);
        }
        __syncthreads();

        short8 a[4], b[4];
        #pragma unroll
        for (int bi = 0; bi < 4; ++bi)
            a[bi] = *(const short8*)&Asm[(waveM * 64 + bi * 16 + cL) * BK + kcs * 8];
        #pragma unroll
        for (int bj = 0; bj < 4; ++bj)
            b[bj] = *(const short8*)&Bsm[(waveN * 64 + bj * 16 + cL) * BK + kcs * 8];

        #pragma unroll
        for (int bi = 0; bi < 4; ++bi)
            #pragma unroll
            for (int bj = 0; bj < 4; ++bj)
                acc[bi][bj] = __builtin_amdgcn_mfma_f32_16x16x32_bf16(
                    a[bi], b[bj], acc[bi][bj], 0, 0, 0);
    }

    const float wv = wp[0], bv = bp[0];
    #pragma unroll
    for (int bi = 0; bi < 4; ++bi) {
        #pragma unroll
        for (int r = 0; r < 4; ++r) {
            const int R    = rowBase + waveM * 64 + bi * 16 + q * 4 + r;
            const float xxv = xxg[R];
            const float rn  = rsqrtf(fmaxf(xxv, EPS));
            const int nrow  = R >> 6;
            float s = 0.f;
            #pragma unroll
            for (int bj = 0; bj < 4; ++bj) {
                const int col = colBase + waveN * 64 + bj * 16 + cL;
                const float dot = acc[bi][bj][r];
                float sim;
                if (col == nrow) {
                    const float ssqv = ssqg[nrow];
                    const float xs   = dot * sqrtf(ssqv);
                    const float d2   = ssqv - 2.f * xs + xxv;
                    const float cs   = ((xs - xxv) * (1.f / 63.f)) * rn *
                                       rsqrtf(fmaxf(d2 * (1.f / 3969.f), EPS));
                    sim = wv * cs + bv;
                    pos[R] = sim;
                } else {
                    sim = wv * (dot * rn) + bv;
                }
                s += __expf(sim);
            }
            #pragma unroll
            for (int off = 1; off < 16; off <<= 1) s += __shfl_xor(s, off);
            if (cL == 0) atomicAdd(&sumexp[R], s);
        }
    }
}

// K3: loss = sum_r log(sumexp[r]) - pos[r]   (sumexp includes the self term)
__global__ __launch_bounds__(256) void finalize_kernel(
    const float* __restrict__ pos, const float* __restrict__ sumexp,
    float* __restrict__ out)
{
    const int tid = blockIdx.x * 256 + threadIdx.x;
    float acc = 0.f;
    for (int r = tid; r < NROWS; r += 64 * 256)
        acc += __logf(sumexp[r]) - pos[r];
    #pragma unroll
    for (int off = 1; off < 64; off <<= 1) acc += __shfl_xor(acc, off);
    __shared__ float red[4];
    if ((threadIdx.x & 63) == 0) red[threadIdx.x >> 6] = acc;
    __syncthreads();
    if (threadIdx.x == 0)
        atomicAdd(out, red[0] + red[1] + red[2] + red[3]);
}

extern "C" void kernel_launch(void* const* d_in, const int* in_sizes, int n_in,
                              void* d_out, int out_size, void* d_ws, size_t ws_size,
                              hipStream_t stream)
{
    const float* x  = (const float*)d_in[0];
    const float* wp = (const float*)d_in[1];
    const float* bp = (const float*)d_in[2];
    float* out = (float*)d_out;

    char* ws = (char*)d_ws;
    size_t off = 0;
    uint16_t* xb     = (uint16_t*)(ws + off); off += (size_t)NROWS * DIM * 2;   // 64 MB
    uint16_t* cmat   = (uint16_t*)(ws + off); off += (size_t)N_SPK * DIM * 2;   // 1 MB
    float*    Sg     = (float*)(ws + off);    off += (size_t)N_SPK * DIM * 4;   // 2 MB
    float*    xxg    = (float*)(ws + off);    off += (size_t)NROWS * 4;
    float*    pos    = (float*)(ws + off);    off += (size_t)NROWS * 4;
    float*    sumexp = (float*)(ws + off);    off += (size_t)NROWS * 4;
    float*    ssqg   = (float*)(ws + off);    off += (size_t)N_SPK * 4;

    hipMemsetAsync(Sg, 0, (size_t)N_SPK * DIM * sizeof(float), stream);
    hipMemsetAsync(sumexp, 0, NROWS * sizeof(float), stream);
    hipMemsetAsync(out, 0, sizeof(float), stream);

    prep_stream<<<N_SPK * 4, 256, 0, stream>>>(x, xb, Sg, xxg);
    centroid_kernel<<<N_SPK, 256, 0, stream>>>(Sg, cmat, ssqg);
    gemm_lse_kernel<<<(NROWS / BM) * (N_SPK / BN), 256, 0, stream>>>(
        xb, cmat, xxg, ssqg, wp, bp, sumexp, pos);
    finalize_kernel<<<64, 256, 0, stream>>>(pos, sumexp, out);
}

// Round 3
// 271.375 us; speedup vs baseline: 1.1473x; 1.0477x over previous
//
#include <hip/hip_runtime.h>
#include <stdint.h>

#define N_SPK 512
#define N_UTT 64
#define DIM   1024
#define NROWS (N_SPK * N_UTT)   // 32768
#define EPS   1e-6f

#define BM 128
#define BN 128
#define BK 32
#define KTILES (DIM / BK)       // 32

typedef __attribute__((ext_vector_type(8))) short short8;
typedef __attribute__((ext_vector_type(4))) float f32x4;

__device__ __forceinline__ uint16_t f2bf(float f) {
    union { float f; uint32_t i; } un; un.f = f;
    uint32_t x = un.i;
    return (uint16_t)((x + 0x7fffu + ((x >> 16) & 1u)) >> 16);
}

// K1a: 4 blocks per speaker, 16 rows each; wave w handles rows w*4..w*4+3.
// All 16 float4 loads issued up-front for MLP, then convert/accumulate/store.
// Per-block partial S written to Sg4[g] slice (plain stores, no memset/atomic).
__global__ __launch_bounds__(256) void prep_stream(
    const float* __restrict__ x, uint16_t* __restrict__ xb,
    float* __restrict__ Sg4, float* __restrict__ xxg)
{
    const int b    = blockIdx.x;
    const int n    = b >> 2;
    const int g    = b & 3;
    const int tid  = threadIdx.x;
    const int lane = tid & 63;
    const int w    = tid >> 6;

    const float* xn  = x  + (size_t)n * N_UTT * DIM;
    uint16_t*    xbn = xb + (size_t)n * N_UTT * DIM;
    const int m0 = g * 16 + w * 4;

    // 16 loads in flight (64 VGPRs)
    float4 v[16];
    #pragma unroll
    for (int i = 0; i < 4; ++i)
        #pragma unroll
        for (int j = 0; j < 4; ++j)
            v[i * 4 + j] = *(const float4*)(xn + (size_t)(m0 + i) * DIM + j * 256 + lane * 4);

    float Sp[16];
    #pragma unroll
    for (int j = 0; j < 16; ++j) Sp[j] = 0.f;
    float xx[4] = {0.f, 0.f, 0.f, 0.f};

    #pragma unroll
    for (int i = 0; i < 4; ++i) {
        #pragma unroll
        for (int j = 0; j < 4; ++j) {
            const float4 q = v[i * 4 + j];
            xx[i] += q.x * q.x + q.y * q.y + q.z * q.z + q.w * q.w;
            Sp[j * 4 + 0] += q.x; Sp[j * 4 + 1] += q.y;
            Sp[j * 4 + 2] += q.z; Sp[j * 4 + 3] += q.w;
            ushort4 o;
            o.x = f2bf(q.x); o.y = f2bf(q.y); o.z = f2bf(q.z); o.w = f2bf(q.w);
            *(ushort4*)(xbn + (size_t)(m0 + i) * DIM + j * 256 + lane * 4) = o;
        }
    }

    #pragma unroll
    for (int i = 0; i < 4; ++i) {
        float t = xx[i];
        #pragma unroll
        for (int off = 1; off < 64; off <<= 1) t += __shfl_xor(t, off);
        if (lane == 0) xxg[n * N_UTT + m0 + i] = t;
    }

    __shared__ float Sh[4][DIM];
    #pragma unroll
    for (int j = 0; j < 4; ++j)
        *(float4*)&Sh[w][j * 256 + lane * 4] =
            make_float4(Sp[j * 4], Sp[j * 4 + 1], Sp[j * 4 + 2], Sp[j * 4 + 3]);
    __syncthreads();

    const int d0 = tid * 4;
    float4 a = *(const float4*)&Sh[0][d0];
    const float4 b1 = *(const float4*)&Sh[1][d0];
    const float4 b2 = *(const float4*)&Sh[2][d0];
    const float4 b3 = *(const float4*)&Sh[3][d0];
    a.x += b1.x + b2.x + b3.x; a.y += b1.y + b2.y + b3.y;
    a.z += b1.z + b2.z + b3.z; a.w += b1.w + b2.w + b3.w;
    *(float4*)(Sg4 + ((size_t)g * N_SPK + n) * DIM + d0) = a;
}

// K1b: sum the 4 partial slices, normalize centroid, write cmat + ssq.
__global__ __launch_bounds__(256) void centroid_kernel(
    const float* __restrict__ Sg4, uint16_t* __restrict__ cmat, float* __restrict__ ssqg)
{
    const int n   = blockIdx.x;
    const int tid = threadIdx.x;
    const int d0  = tid * 4;

    float4 S = *(const float4*)(Sg4 + ((size_t)0 * N_SPK + n) * DIM + d0);
    #pragma unroll
    for (int g = 1; g < 4; ++g) {
        const float4 p = *(const float4*)(Sg4 + ((size_t)g * N_SPK + n) * DIM + d0);
        S.x += p.x; S.y += p.y; S.z += p.z; S.w += p.w;
    }

    float css = S.x * S.x + S.y * S.y + S.z * S.z + S.w * S.w;
    #pragma unroll
    for (int off = 1; off < 64; off <<= 1) css += __shfl_xor(css, off);
    __shared__ float red[4];
    if ((tid & 63) == 0) red[tid >> 6] = css;
    __syncthreads();
    const float ssq = red[0] + red[1] + red[2] + red[3];

    const float scale = rsqrtf(fmaxf(ssq * (1.0f / 4096.f), EPS)) * (1.0f / 64.f);
    ushort4 o;
    o.x = f2bf(S.x * scale); o.y = f2bf(S.y * scale);
    o.z = f2bf(S.z * scale); o.w = f2bf(S.w * scale);
    *(ushort4*)(cmat + (size_t)n * DIM + d0) = o;
    if (tid == 0) ssqg[n] = ssq;
}

// K2: bf16 MFMA GEMM (A = xb [32768 x 1024], B^T = cmat [512 x 1024]).
// Epilogue: off-diag sim = w*dot*rn + b; diag reconstructs cos_self from
// (dot*|S|, xx, ssq), stores pos[R]. Row partial sums of exp combined across
// the two waveN halves via LDS, plain-stored to sumexp4[ct] (no memset/atomic).
__global__ __launch_bounds__(256) void gemm_lse_kernel(
    const uint16_t* __restrict__ xb, const uint16_t* __restrict__ cmat,
    const float* __restrict__ xxg, const float* __restrict__ ssqg,
    const float* __restrict__ wp, const float* __restrict__ bp,
    float* __restrict__ sumexp4, float* __restrict__ pos)
{
    __shared__ uint16_t Asm[BM * BK];   // 8 KB
    __shared__ uint16_t Bsm[BN * BK];   // 8 KB
    __shared__ float    SeLDS[BM];      // 512 B, epilogue combine

    const int tid   = threadIdx.x;
    const int lane  = tid & 63;
    const int wid   = tid >> 6;
    const int waveM = wid >> 1;
    const int waveN = wid & 1;

    const int bid = blockIdx.x;
    const int rt  = (bid & 7) | ((bid >> 5) << 3);
    const int ct  = (bid >> 3) & 3;

    const int rowBase = rt * BM;
    const int colBase = ct * BN;

    const uint16_t* gA[2];
    const uint16_t* gB[2];
    #pragma unroll
    for (int i = 0; i < 2; ++i) {
        const int s    = i * 256 + tid;
        const int srow = s >> 2;
        const int kc   = (s & 3) ^ ((srow >> 1) & 3);
        gA[i] = xb   + (size_t)(rowBase + srow) * DIM + kc * 8;
        gB[i] = cmat + (size_t)(colBase + srow) * DIM + kc * 8;
    }

    f32x4 acc[4][4];
    #pragma unroll
    for (int i = 0; i < 4; ++i)
        #pragma unroll
        for (int j = 0; j < 4; ++j)
            acc[i][j] = (f32x4){0.f, 0.f, 0.f, 0.f};

    const int cL  = lane & 15;
    const int q   = lane >> 4;
    const int key = (cL >> 1) & 3;
    const int kcs = q ^ key;

    for (int kt = 0; kt < KTILES; ++kt) {
        __syncthreads();
        const int ko = kt * BK;
        #pragma unroll
        for (int i = 0; i < 2; ++i) {
            __builtin_amdgcn_global_load_lds(
                (const __attribute__((address_space(1))) void*)(gA[i] + ko),
                (__attribute__((address_space(3))) void*)(&Asm[(i * 256 + wid * 64) * 8]),
                16, 0, 0);
            __builtin_amdgcn_global_load_lds(
                (const __attribute__((address_space(1))) void*)(gB[i] + ko),
                (__attribute__((address_space(3))) void*)(&Bsm[(i * 256 + wid * 64) * 8]),
                16, 0, 0);
        }
        __syncthreads();

        short8 a[4], b[4];
        #pragma unroll
        for (int bi = 0; bi < 4; ++bi)
            a[bi] = *(const short8*)&Asm[(waveM * 64 + bi * 16 + cL) * BK + kcs * 8];
        #pragma unroll
        for (int bj = 0; bj < 4; ++bj)
            b[bj] = *(const short8*)&Bsm[(waveN * 64 + bj * 16 + cL) * BK + kcs * 8];

        #pragma unroll
        for (int bi = 0; bi < 4; ++bi)
            #pragma unroll
            for (int bj = 0; bj < 4; ++bj)
                acc[bi][bj] = __builtin_amdgcn_mfma_f32_16x16x32_bf16(
                    a[bi], b[bj], acc[bi][bj], 0, 0, 0);
    }

    const float wv = wp[0], bv = bp[0];
    float srow[16];
    #pragma unroll
    for (int bi = 0; bi < 4; ++bi) {
        #pragma unroll
        for (int r = 0; r < 4; ++r) {
            const int R     = rowBase + waveM * 64 + bi * 16 + q * 4 + r;
            const float xxv = xxg[R];
            const float rn  = rsqrtf(fmaxf(xxv, EPS));
            const int nrow  = R >> 6;
            float s = 0.f;
            #pragma unroll
            for (int bj = 0; bj < 4; ++bj) {
                const int col = colBase + waveN * 64 + bj * 16 + cL;
                const float dot = acc[bi][bj][r];
                float sim;
                if (col == nrow) {
                    const float ssqv = ssqg[nrow];
                    const float xs   = dot * sqrtf(ssqv);
                    const float d2   = ssqv - 2.f * xs + xxv;
                    const float cs   = ((xs - xxv) * (1.f / 63.f)) * rn *
                                       rsqrtf(fmaxf(d2 * (1.f / 3969.f), EPS));
                    sim = wv * cs + bv;
                    pos[R] = sim;
                } else {
                    sim = wv * (dot * rn) + bv;
                }
                s += __expf(sim);
            }
            #pragma unroll
            for (int off = 1; off < 16; off <<= 1) s += __shfl_xor(s, off);
            srow[bi * 4 + r] = s;
        }
    }

    // combine waveN halves via LDS; one plain store per (ct, row)
    if (waveN == 1 && cL == 0) {
        #pragma unroll
        for (int bi = 0; bi < 4; ++bi)
            #pragma unroll
            for (int r = 0; r < 4; ++r)
                SeLDS[waveM * 64 + bi * 16 + q * 4 + r] = srow[bi * 4 + r];
    }
    __syncthreads();
    if (waveN == 0 && cL == 0) {
        #pragma unroll
        for (int bi = 0; bi < 4; ++bi)
            #pragma unroll
            for (int r = 0; r < 4; ++r) {
                const int lr = waveM * 64 + bi * 16 + q * 4 + r;
                sumexp4[(size_t)ct * NROWS + rowBase + lr] = srow[bi * 4 + r] + SeLDS[lr];
            }
    }
}

// K3: single block; loss = sum_r log(sum_ct se4) - pos[r]; direct store to out.
__global__ __launch_bounds__(1024) void finalize_kernel(
    const float* __restrict__ pos, const float* __restrict__ se4,
    float* __restrict__ out)
{
    const int tid = threadIdx.x;
    float acc = 0.f;
    for (int r = tid; r < NROWS; r += 1024) {
        const float s = se4[r] + se4[NROWS + r] + se4[2 * NROWS + r] + se4[3 * NROWS + r];
        acc += __logf(s) - pos[r];
    }
    #pragma unroll
    for (int off = 1; off < 64; off <<= 1) acc += __shfl_xor(acc, off);
    __shared__ float red[16];
    if ((tid & 63) == 0) red[tid >> 6] = acc;
    __syncthreads();
    if (tid == 0) {
        float t = 0.f;
        #pragma unroll
        for (int i = 0; i < 16; ++i) t += red[i];
        out[0] = t;
    }
}

extern "C" void kernel_launch(void* const* d_in, const int* in_sizes, int n_in,
                              void* d_out, int out_size, void* d_ws, size_t ws_size,
                              hipStream_t stream)
{
    const float* x  = (const float*)d_in[0];
    const float* wp = (const float*)d_in[1];
    const float* bp = (const float*)d_in[2];
    float* out = (float*)d_out;

    char* ws = (char*)d_ws;
    size_t off = 0;
    uint16_t* xb      = (uint16_t*)(ws + off); off += (size_t)NROWS * DIM * 2;     // 64 MB
    uint16_t* cmat    = (uint16_t*)(ws + off); off += (size_t)N_SPK * DIM * 2;     // 1 MB
    float*    Sg4     = (float*)(ws + off);    off += (size_t)4 * N_SPK * DIM * 4; // 8 MB
    float*    xxg     = (float*)(ws + off);    off += (size_t)NROWS * 4;
    float*    pos     = (float*)(ws + off);    off += (size_t)NROWS * 4;
    float*    sumexp4 = (float*)(ws + off);    off += (size_t)4 * NROWS * 4;
    float*    ssqg    = (float*)(ws + off);    off += (size_t)N_SPK * 4;

    prep_stream<<<N_SPK * 4, 256, 0, stream>>>(x, xb, Sg4, xxg);
    centroid_kernel<<<N_SPK, 256, 0, stream>>>(Sg4, cmat, ssqg);
    gemm_lse_kernel<<<(NROWS / BM) * (N_SPK / BN), 256, 0, stream>>>(
        xb, cmat, xxg, ssqg, wp, bp, sumexp4, pos);
    finalize_kernel<<<1, 1024, 0, stream>>>(pos, sumexp4, out);
}